// Round 16
// baseline (113.272 us; speedup 1.0000x reference)
//
#include <hip/hip_runtime.h>

// QuantizeEMAReset forward (eval): VQ quantize + commit loss + perplexity/usage.
// z: [16,4096,64] fp32 -> N=65536 tokens, C=64. codebook: [1024,64] fp32.
// out: [z_q_bar (4194304 f32), commit_loss, ppl, usage] flat.
//
// R16: producer/consumer wave specialization. 5 waves/block: wave 4 (producer)
// DMAs each 4KB codebook tile ONCE into a shared 8-slot LDS ring and publishes
// a monotone tiles_ready counter after counted vmcnt; 4 consumer waves (64
// tokens) spin on the counter (broadcast LDS read + s_sleep) then compute via
// pure LDS+VALU+MFMA -- consumers execute ZERO VMEM ops in the loop, so the
// R9/R10/R15 failure mode (register spill -> scratch ops corrupt counted
// vmcnt) is structurally impossible. Slot reuse guarded by per-slot consumed[]
// LDS atomics (classic bounded buffer). DMA traffic 1GB -> 256MB; rolled
// loops (no giant unrolled body). Numerics = R13 exactly (absmax 0.0 proven):
// fp16-split 6-MFMA chains, top-2 with indices, O(2) in-lane exact rescue.
//
// ws float-index map:
//   [0,1024)       cnorm
//   [1024,2048)    counts
//   [2048,3072)    loss partials (1024 blocks)
//   [20480,86016)  cbhl tile stream: 64 tiles x 2048 halves (hi 1KB | lo 1KB)

typedef _Float16 half8 __attribute__((ext_vector_type(8)));
typedef float f32x4 __attribute__((ext_vector_type(4)));

#define NTOK 65536
#define KCODE 1024
#define OUT_SCALARS 4194304
#define MARGIN 1e-3f

#define WS_CNT   1024
#define WS_LOSS  2048
#define WS_CBHL  20480

static __device__ __forceinline__ unsigned int order_key(float f) {
    unsigned int u = __float_as_uint(f);
    unsigned int mask = (u >> 31) ? 0xFFFFFFFFu : 0x80000000u;
    return u ^ mask;   // monotone: a<b (float) <=> key(a)<key(b) (uint)
}
static __device__ __forceinline__ float key_to_float(unsigned int k) {
    unsigned int u = (k & 0x80000000u) ? (k ^ 0x80000000u) : ~k;
    return __uint_as_float(u);   // inverse of order_key
}
static __device__ __forceinline__ unsigned long long umin64(unsigned long long a,
                                                            unsigned long long b) {
    return a < b ? a : b;
}
static __device__ __forceinline__ unsigned long long umax64(unsigned long long a,
                                                            unsigned long long b) {
    return a > b ? a : b;
}

__global__ void prep_kernel(const float* __restrict__ cb, float* __restrict__ ws) {
    const int k = blockIdx.x * 256 + threadIdx.x;   // 0..1023
    const float4* cb4 = (const float4*)cb;
    float s = 0.f;
#pragma unroll
    for (int j = 0; j < 16; ++j) {
        float4 v = cb4[k * 16 + j];
        s = fmaf(v.x, v.x, s);
        s = fmaf(v.y, v.y, s);
        s = fmaf(v.z, v.z, s);
        s = fmaf(v.w, v.w, s);
    }
    ws[k] = s;             // cnorm: exact R1 chain
    ws[WS_CNT + k] = 0.f;  // zero histogram

    // swizzled tile stream: tile = k>>4, c = k&15
    _Float16* base = (_Float16*)(ws + WS_CBHL) + (size_t)(k >> 4) * 2048 + (k & 15) * 64;
    const int c = k & 15;
#pragma unroll
    for (int d8 = 0; d8 < 8; ++d8) {
        float4 a = cb4[k * 16 + 2 * d8], b = cb4[k * 16 + 2 * d8 + 1];
        float xf[8] = {a.x, a.y, a.z, a.w, b.x, b.y, b.z, b.w};
        half8 h, lo;
#pragma unroll
        for (int i = 0; i < 8; ++i) {
            _Float16 hi = (_Float16)xf[i];
            h[i] = hi;
            lo[i] = (_Float16)((xf[i] - (float)hi) * 4096.f);  // scaled: no f16 denorm flush
        }
        const int pos = ((d8 + c) & 7) * 8;   // 16B-slot rotation (bank spread)
        *(half8*)(base + pos) = h;
        *(half8*)(base + 1024 + pos) = lo;
    }
}

__launch_bounds__(320, 4)
__global__ void quant_kernel(const float* __restrict__ z,
                             const float* __restrict__ cb,
                             float* __restrict__ out,
                             float* __restrict__ ws) {
    const int t = threadIdx.x, blk = blockIdx.x;
    const int w = t >> 6, l = t & 63;
    const int cl = l & 15, g = l >> 4;
    const bool prod = (w == 4);
    const int tok0 = blk * 64;
    const int tokL = w * 16 + cl;             // consumers: 0..63
    const int tokG = tok0 + (prod ? 0 : tokL);

    __shared__ __align__(16) _Float16 ring[8][2048];   // shared 8-slot ring, 32KB
    __shared__ __align__(16) float cn_lds[1024];
    __shared__ int win[64];
    __shared__ float lsum[64];
    __shared__ int tiles_ready;     // count of complete tiles
    __shared__ int consumed[8];     // per-slot consumption count

    if (t == 0) tiles_ready = 0;
    if (t < 8) consumed[t] = 0;
    if (t < 256) *(float4*)&cn_lds[t * 4] = *(const float4*)(ws + t * 4);

    // ---- consumer B fragments: ONE token set of 16 (R13-proven) ----
    half8 zh[2], zl[2];
    if (!prod) {
        const float4* z4 = (const float4*)z + (size_t)tokG * 16;
#pragma unroll
        for (int q = 0; q < 2; ++q) {
            float4 a = z4[2 * g + 8 * q], b = z4[2 * g + 8 * q + 1];
            float xf[8] = {a.x, a.y, a.z, a.w, b.x, b.y, b.z, b.w};
#pragma unroll
            for (int i = 0; i < 8; ++i) {
                _Float16 h = (_Float16)xf[i];
                zh[q][i] = h;
                zl[q][i] = (_Float16)((xf[i] - (float)h) * 4096.f);
            }
        }
    }
    __syncthreads();   // flags + cn_lds visible to all waves

    float d1 = 3.4e38f, d2 = 3.4e38f;
    int idx1 = 0, idx2 = 0;

    if (prod) {
        // ================= producer wave =================
        const char* src = (const char*)(ws + WS_CBHL) + l * 16;
        volatile int* vcons = consumed;
        volatile int* vtr = &tiles_ready;
        for (int T = 0; T < 64; ++T) {
            const int s = T & 7;
            if (T >= 8) {
                const int need = (T >> 3) * 4;   // 4 consumers per prior epoch
                while (vcons[s] < need) __builtin_amdgcn_s_sleep(1);
            }
            __builtin_amdgcn_sched_barrier(0);
#pragma unroll
            for (int q = 0; q < 4; ++q)
                __builtin_amdgcn_global_load_lds(
                    (const __attribute__((address_space(1))) void*)(src + T * 4096 + q * 1024),
                    (__attribute__((address_space(3))) void*)&ring[s][q * 512], 16, 0, 0);
            asm volatile("s_waitcnt vmcnt(16)" ::: "memory");   // tiles <= T-4 done
            if (l == 0 && T >= 4) *vtr = T - 3;
        }
        asm volatile("s_waitcnt vmcnt(8)" ::: "memory");
        if (l == 0) *vtr = 62;
        asm volatile("s_waitcnt vmcnt(4)" ::: "memory");
        if (l == 0) *vtr = 63;
        asm volatile("s_waitcnt vmcnt(0)" ::: "memory");
        if (l == 0) *vtr = 64;
    } else {
        // ================= consumer waves =================
        const int rot = (g + cl) & 7;
        const int o0 = cl * 64 + rot * 8;
        const int o1 = cl * 64 + (rot ^ 4) * 8;
        volatile int* vtr = &tiles_ready;

        for (int T = 0; T < 64; ++T) {
            while (*vtr < T + 1) __builtin_amdgcn_s_sleep(1);
            __builtin_amdgcn_sched_barrier(0);   // no LDS read hoists above spin
            const _Float16* tp = &ring[T & 7][0];
            half8 H0 = *(const half8*)(tp + o0);
            half8 H1 = *(const half8*)(tp + o1);
            half8 L0 = *(const half8*)(tp + 1024 + o0);
            half8 L1 = *(const half8*)(tp + 1024 + o1);
            float4 cnv = *(const float4*)&cn_lds[T * 16 + 4 * g];
            __builtin_amdgcn_sched_barrier(0);   // signal stays after the reads
            if (l == 0) atomicAdd(&consumed[T & 7], 1);   // DS in-order: lands after reads

            f32x4 a1 = {0.f, 0.f, 0.f, 0.f}, a2 = {0.f, 0.f, 0.f, 0.f};
            a1 = __builtin_amdgcn_mfma_f32_16x16x32_f16(H0, zh[0], a1, 0, 0, 0);
            a1 = __builtin_amdgcn_mfma_f32_16x16x32_f16(H1, zh[1], a1, 0, 0, 0);
            a2 = __builtin_amdgcn_mfma_f32_16x16x32_f16(H0, zl[0], a2, 0, 0, 0);
            a2 = __builtin_amdgcn_mfma_f32_16x16x32_f16(H1, zl[1], a2, 0, 0, 0);
            a2 = __builtin_amdgcn_mfma_f32_16x16x32_f16(L0, zh[0], a2, 0, 0, 0);
            a2 = __builtin_amdgcn_mfma_f32_16x16x32_f16(L1, zh[1], a2, 0, 0, 0);

            const float cna[4] = {cnv.x, cnv.y, cnv.z, cnv.w};
#pragma unroll
            for (int r = 0; r < 4; ++r) {
                float dot = fmaf(a2[r], 2.44140625e-4f, a1[r]);
                float d = fmaf(-2.f, dot, cna[r]);
                const int kidx = T * 16 + 4 * g + r;
                bool lt = d < d1;
                bool mid = d < d2;
                idx2 = lt ? idx1 : (mid ? kidx : idx2);   // old values: order matters
                d2 = fminf(d2, fmaxf(d, d1));
                idx1 = lt ? kidx : idx1;
                d1 = fminf(d1, d);
            }
        }
    }

    // ---- keyed top-2 merge across the 4 lanes of each token (xor 16, 32) ----
    if (!prod) {
        unsigned long long k1 = ((unsigned long long)order_key(d1) << 32) | (unsigned)idx1;
        unsigned long long k2 = ((unsigned long long)order_key(d2) << 32) | (unsigned)idx2;
#pragma unroll
        for (int off = 16; off <= 32; off <<= 1) {
            unsigned long long ok1 = __shfl_xor(k1, off, 64);
            unsigned long long ok2 = __shfl_xor(k2, off, 64);
            unsigned long long lo = umin64(k1, ok1);
            unsigned long long hi = umax64(k1, ok1);
            k2 = umin64(hi, umin64(k2, ok2));
            k1 = lo;
        }

        if (l < 16) {
            int fidx = (int)(unsigned)(k1 & 0xFFFFFFFFull);
            const float d1f = key_to_float((unsigned)(k1 >> 32));
            const float d2f = key_to_float((unsigned)(k2 >> 32));
            if (d2f - d1f < MARGIN) {
                // exact fp32 rescore of the two candidates (bit-exact R1 chain)
                const int ia = fidx;
                const int ib = (int)(unsigned)(k2 & 0xFFFFFFFFull);
                const float4* zr = (const float4*)z + (size_t)tokG * 16;
                const float4* ca = (const float4*)cb + (size_t)ia * 16;
                const float4* cbp = (const float4*)cb + (size_t)ib * 16;
                float sa = 0.f, sb = 0.f;
#pragma unroll
                for (int j = 0; j < 16; ++j) {
                    float4 xv = zr[j];
                    float4 va = ca[j], vb = cbp[j];
                    sa = fmaf(xv.x, va.x, sa); sb = fmaf(xv.x, vb.x, sb);
                    sa = fmaf(xv.y, va.y, sa); sb = fmaf(xv.y, vb.y, sb);
                    sa = fmaf(xv.z, va.z, sa); sb = fmaf(xv.z, vb.z, sb);
                    sa = fmaf(xv.w, va.w, sa); sb = fmaf(xv.w, vb.w, sb);
                }
                const float ea = fmaf(-2.f, sa, cn_lds[ia]);   // exact R1 distance
                const float eb = fmaf(-2.f, sb, cn_lds[ib]);
                const unsigned long long ka =
                    ((unsigned long long)order_key(ea) << 32) | (unsigned)ia;
                const unsigned long long kb =
                    ((unsigned long long)order_key(eb) << 32) | (unsigned)ib;
                fidx = (int)(unsigned)(umin64(ka, kb) & 0xFFFFFFFFull);
            }
            win[tokL] = fidx;
            atomicAdd(&ws[WS_CNT + fidx], 1.f);   // integer-valued: exact, order-indep
        }
    }
    __syncthreads();

    // ---- fused epilogue: z_q_bar + commit-loss partial (threads 0-255) ----
    if (t < 256) {
        const int tokr = t >> 2, fb = (t & 3) * 4;   // 4 threads per token
        const int idx = win[tokr];
        const float4* zr = (const float4*)z + (size_t)(tok0 + tokr) * 16;
        const float4* cq = (const float4*)cb + (size_t)idx * 16;
        float4* o4 = (float4*)out + (size_t)(tok0 + tokr) * 16;
        float ss = 0.f;
#pragma unroll
        for (int j = 0; j < 4; ++j) {
            float4 xv = zr[fb + j];
            float4 qv = cq[fb + j];
            float4 ov; float dx;
            dx = qv.x - xv.x; ov.x = xv.x + dx; ss = fmaf(dx, dx, ss);
            dx = qv.y - xv.y; ov.y = xv.y + dx; ss = fmaf(dx, dx, ss);
            dx = qv.z - xv.z; ov.z = xv.z + dx; ss = fmaf(dx, dx, ss);
            dx = qv.w - xv.w; ov.w = xv.w + dx; ss = fmaf(dx, dx, ss);
            o4[fb + j] = ov;
        }
        ss += __shfl_down(ss, 2, 64);   // quadrants: (q0+q2)
        ss += __shfl_down(ss, 1, 64);   // + (q1+q3)
        if ((t & 3) == 0) lsum[tokr] = ss * (1.f / 64.f);
    }
    __syncthreads();
    if (t < 64) {
        float v = lsum[t];
#pragma unroll
        for (int off = 32; off > 0; off >>= 1) v += __shfl_down(v, off, 64);
        if (t == 0) ws[WS_LOSS + blk] = v;
    }
}

// Reduce-only final (shuffle trees; R12/R13-proven logic). 1 block x 1024 thr.
__global__ void final_kernel(const float* __restrict__ ws, float* __restrict__ out) {
    const int t = threadIdx.x;          // 0..1023
    const int l = t & 63, wv = t >> 6;  // 16 waves
    __shared__ float rbuf[16];

#define BLOCK_REDUCE(VAR, EXPR)                                             \
    float VAR;                                                              \
    {                                                                       \
        float v_ = (EXPR);                                                  \
        _Pragma("unroll")                                                   \
        for (int off = 32; off > 0; off >>= 1) v_ += __shfl_down(v_, off, 64); \
        if (l == 0) rbuf[wv] = v_;                                          \
        __syncthreads();                                                    \
        float r_ = (t < 16) ? rbuf[t] : 0.f;                                \
        if (wv == 0) {                                                      \
            _Pragma("unroll")                                               \
            for (int off = 8; off > 0; off >>= 1) r_ += __shfl_down(r_, off, 64); \
            if (l == 0) rbuf[0] = r_;                                       \
        }                                                                   \
        __syncthreads();                                                    \
        VAR = rbuf[0];                                                      \
        __syncthreads();                                                    \
    }

    const float c = ws[WS_CNT + t];
    BLOCK_REDUCE(totraw, c)
    const float total = fmaxf(totraw, 1e-6f);
    const float p = c / total;
    BLOCK_REDUCE(ent, p * logf(p + 1e-7f))
    BLOCK_REDUCE(used, (c >= 1.f) ? 1.f : 0.f)
    BLOCK_REDUCE(loss, ws[WS_LOSS + t])
#undef BLOCK_REDUCE

    if (t == 0) {
        out[OUT_SCALARS + 0] = loss * (1.f / (float)NTOK);
        out[OUT_SCALARS + 1] = expf(-ent);
        out[OUT_SCALARS + 2] = used * (1.f / (float)KCODE);
    }
}

extern "C" void kernel_launch(void* const* d_in, const int* in_sizes, int n_in,
                              void* d_out, int out_size, void* d_ws, size_t ws_size,
                              hipStream_t stream) {
    const float* z  = (const float*)d_in[0];
    const float* cb = (const float*)d_in[1];
    float* out = (float*)d_out;
    float* ws  = (float*)d_ws;   // ~344 KB used

    prep_kernel <<<4, 256, 0, stream>>>(cb, ws);
    quant_kernel<<<NTOK / 64, 320, 0, stream>>>(z, cb, out, ws);
    final_kernel<<<1, 1024, 0, stream>>>(ws, out);
}

// Round 17
// 85.381 us; speedup vs baseline: 1.3267x; 1.3267x over previous
//
#include <hip/hip_runtime.h>

// QuantizeEMAReset forward (eval): VQ quantize + commit loss + perplexity/usage.
// z: [16,4096,64] fp32 -> N=65536 tokens, C=64. codebook: [1024,64] fp32.
// out: [z_q_bar (4194304 f32), commit_loss, ppl, usage] flat.
//
// R17 = R11's quant structure (fastest proven: 70us; 3-slot x 2-tile ring,
// vmcnt(2)+s_barrier per 2-tile phase, 28.75KB LDS) + R13's top-2/O(2)
// in-lane exact rescue (no separate rescue dispatch) + reduce-only final
// + __launch_bounds__(256,5): 5 blocks/CU (R11 left (256,4) headroom; more
// TLP against the ds_read->MFMA->argmin dependent-chain stalls).
// 2-token-set / 32x32 variants are OFF-LIMITS: three builds (R9/R10/R15)
// produced unexplained ppl corruption incl. at VGPR=84 (no spill) -- the
// mechanism is unidentified, so that register profile is quarantined.
//
// ws float-index map:
//   [0,1024)       cnorm
//   [1024,2048)    counts
//   [2048,3072)    loss partials (1024 blocks)
//   [20480,86016)  cbhl tile stream: 64 tiles x 2048 halves (hi 1KB | lo 1KB)

typedef _Float16 half8 __attribute__((ext_vector_type(8)));
typedef float f32x4 __attribute__((ext_vector_type(4)));

#define NTOK 65536
#define KCODE 1024
#define OUT_SCALARS 4194304
#define MARGIN 1e-3f

#define WS_CNT   1024
#define WS_LOSS  2048
#define WS_CBHL  20480

static __device__ __forceinline__ unsigned int order_key(float f) {
    unsigned int u = __float_as_uint(f);
    unsigned int mask = (u >> 31) ? 0xFFFFFFFFu : 0x80000000u;
    return u ^ mask;   // monotone: a<b (float) <=> key(a)<key(b) (uint)
}
static __device__ __forceinline__ float key_to_float(unsigned int k) {
    unsigned int u = (k & 0x80000000u) ? (k ^ 0x80000000u) : ~k;
    return __uint_as_float(u);   // inverse of order_key
}
static __device__ __forceinline__ unsigned long long umin64(unsigned long long a,
                                                            unsigned long long b) {
    return a < b ? a : b;
}
static __device__ __forceinline__ unsigned long long umax64(unsigned long long a,
                                                            unsigned long long b) {
    return a > b ? a : b;
}

__global__ void prep_kernel(const float* __restrict__ cb, float* __restrict__ ws) {
    const int k = blockIdx.x * 256 + threadIdx.x;   // 0..1023
    const float4* cb4 = (const float4*)cb;
    float s = 0.f;
#pragma unroll
    for (int j = 0; j < 16; ++j) {
        float4 v = cb4[k * 16 + j];
        s = fmaf(v.x, v.x, s);
        s = fmaf(v.y, v.y, s);
        s = fmaf(v.z, v.z, s);
        s = fmaf(v.w, v.w, s);
    }
    ws[k] = s;             // cnorm: exact R1 chain
    ws[WS_CNT + k] = 0.f;  // zero histogram

    // swizzled tile stream: tile = k>>4, c = k&15
    _Float16* base = (_Float16*)(ws + WS_CBHL) + (size_t)(k >> 4) * 2048 + (k & 15) * 64;
    const int c = k & 15;
#pragma unroll
    for (int d8 = 0; d8 < 8; ++d8) {
        float4 a = cb4[k * 16 + 2 * d8], b = cb4[k * 16 + 2 * d8 + 1];
        float xf[8] = {a.x, a.y, a.z, a.w, b.x, b.y, b.z, b.w};
        half8 h, lo;
#pragma unroll
        for (int i = 0; i < 8; ++i) {
            _Float16 hi = (_Float16)xf[i];
            h[i] = hi;
            lo[i] = (_Float16)((xf[i] - (float)hi) * 4096.f);  // scaled: no f16 denorm flush
        }
        const int pos = ((d8 + c) & 7) * 8;   // 16B-slot rotation (bank spread)
        *(half8*)(base + pos) = h;
        *(half8*)(base + 1024 + pos) = lo;
    }
}

__launch_bounds__(256, 5)
__global__ void quant_kernel(const float* __restrict__ z,
                             const float* __restrict__ cb,
                             float* __restrict__ out,
                             float* __restrict__ ws) {
    const int t = threadIdx.x, blk = blockIdx.x;
    const int w = t >> 6, l = t & 63;
    const int cl = l & 15, g = l >> 4;
    const int tok0 = blk * 64;
    const int tokL = w * 16 + cl;
    const int tokG = tok0 + tokL;

    __shared__ __align__(16) _Float16 tiles[3][2][2048];  // 3-slot x 2-tile ring, 24KB
    __shared__ __align__(16) float cn_lds[1024];
    __shared__ int win[64];
    __shared__ float lsum[64];

    // ---- stage cnorm to LDS ----
    *(float4*)&cn_lds[t * 4] = *(const float4*)(ws + t * 4);

    // ---- B fragments: ONE token set of 16 (persistent regs; proven) ----
    half8 zh[2], zl[2];
    {
        const float4* z4 = (const float4*)z + (size_t)tokG * 16;
#pragma unroll
        for (int q = 0; q < 2; ++q) {
            float4 a = z4[2 * g + 8 * q], b = z4[2 * g + 8 * q + 1];
            float xf[8] = {a.x, a.y, a.z, a.w, b.x, b.y, b.z, b.w};
#pragma unroll
            for (int i = 0; i < 8; ++i) {
                _Float16 h = (_Float16)xf[i];
                zh[q][i] = h;
                zl[q][i] = (_Float16)((xf[i] - (float)h) * 4096.f);
            }
        }
    }

    // PIN: z-loads + LDS writes done; in-loop vmcnt counts ONLY DMA stream.
    asm volatile("s_waitcnt vmcnt(0) lgkmcnt(0)" ::: "memory");
    __builtin_amdgcn_sched_barrier(0);

    // per-wave DMA src: wave w stages quarter w of each tile (1KB/tile)
    const char* dma_src = (const char*)(ws + WS_CBHL) + w * 1024 + l * 16;
    const int rot = (g + cl) & 7;
    const int o0 = cl * 64 + rot * 8;
    const int o1 = cl * 64 + (rot ^ 4) * 8;

    // prologue: groups 0,1 in flight (2 tiles each -> 4 DMAs/wave)
#pragma unroll
    for (int p = 0; p < 2; ++p)
#pragma unroll
        for (int u = 0; u < 2; ++u)
            __builtin_amdgcn_global_load_lds(
                (const __attribute__((address_space(1))) void*)(dma_src + (p * 2 + u) * 4096),
                (__attribute__((address_space(3))) void*)&tiles[p][u][w * 512], 16, 0, 0);

    float d1 = 3.4e38f, d2 = 3.4e38f;
    int idx1 = 0, idx2 = 0;

#define TILE_COMPUTE(ti, TP)                                                          \
    {                                                                                 \
        const _Float16* tp = (TP);                                                    \
        half8 H0 = *(const half8*)(tp + o0);                                          \
        half8 H1 = *(const half8*)(tp + o1);                                          \
        half8 L0 = *(const half8*)(tp + 1024 + o0);                                   \
        half8 L1 = *(const half8*)(tp + 1024 + o1);                                   \
        float4 cnv = *(const float4*)&cn_lds[(ti) * 16 + 4 * g];                      \
        const float cna[4] = {cnv.x, cnv.y, cnv.z, cnv.w};                            \
        f32x4 a1 = {0.f,0.f,0.f,0.f}, a2 = {0.f,0.f,0.f,0.f};                         \
        a1 = __builtin_amdgcn_mfma_f32_16x16x32_f16(H0, zh[0], a1, 0, 0, 0);          \
        a1 = __builtin_amdgcn_mfma_f32_16x16x32_f16(H1, zh[1], a1, 0, 0, 0);          \
        a2 = __builtin_amdgcn_mfma_f32_16x16x32_f16(H0, zl[0], a2, 0, 0, 0);          \
        a2 = __builtin_amdgcn_mfma_f32_16x16x32_f16(H1, zl[1], a2, 0, 0, 0);          \
        a2 = __builtin_amdgcn_mfma_f32_16x16x32_f16(L0, zh[0], a2, 0, 0, 0);          \
        a2 = __builtin_amdgcn_mfma_f32_16x16x32_f16(L1, zh[1], a2, 0, 0, 0);          \
        _Pragma("unroll")                                                             \
        for (int r = 0; r < 4; ++r) {                                                 \
            float dot = fmaf(a2[r], 2.44140625e-4f, a1[r]);                           \
            float d = fmaf(-2.f, dot, cna[r]);                                        \
            const int kidx = (ti) * 16 + 4 * g + r;                                   \
            bool lt = d < d1;                                                         \
            bool mid = d < d2;                                                        \
            idx2 = lt ? idx1 : (mid ? kidx : idx2);   /* old values: order matters */ \
            d2 = fminf(d2, fmaxf(d, d1));                                             \
            idx1 = lt ? kidx : idx1;                                                  \
            d1 = fminf(d1, d);                                                        \
        }                                                                             \
    }

    // phase P: vmcnt (group P landed), barrier, issue group P+2, compute 2 tiles.
#define PHASE(P, SLOT, SLOT2, VM, ISSUE)                                              \
    {                                                                                 \
        asm volatile("s_waitcnt vmcnt(" VM ")" ::: "memory");                         \
        asm volatile("s_barrier" ::: "memory");                                       \
        if (ISSUE) {                                                                  \
            _Pragma("unroll")                                                         \
            for (int u = 0; u < 2; ++u)                                               \
                __builtin_amdgcn_global_load_lds(                                     \
                    (const __attribute__((address_space(1))) void*)(dma_src + (((P) + 2) * 2 + u) * 4096), \
                    (__attribute__((address_space(3))) void*)&tiles[SLOT2][u][w * 512], \
                    16, 0, 0);                                                        \
        }                                                                             \
        TILE_COMPUTE((P) * 2 + 0, &tiles[SLOT][0][0])                                 \
        TILE_COMPUTE((P) * 2 + 1, &tiles[SLOT][1][0])                                 \
    }

    // phases 0..29 (10 x 3, static slots), issuing groups 2..31
    for (int i3 = 0; i3 < 30; i3 += 3) {
        PHASE(i3 + 0, 0, 2, "2", 1)
        PHASE(i3 + 1, 1, 0, "2", 1)
        PHASE(i3 + 2, 2, 1, "2", 1)
    }
    PHASE(30, 0, 0, "2", 0)
    PHASE(31, 1, 0, "0", 0)
#undef PHASE
#undef TILE_COMPUTE

    // ---- keyed top-2 merge across the 4 lanes of each token (xor 16, 32) ----
    unsigned long long k1 = ((unsigned long long)order_key(d1) << 32) | (unsigned)idx1;
    unsigned long long k2 = ((unsigned long long)order_key(d2) << 32) | (unsigned)idx2;
#pragma unroll
    for (int off = 16; off <= 32; off <<= 1) {
        unsigned long long ok1 = __shfl_xor(k1, off, 64);
        unsigned long long ok2 = __shfl_xor(k2, off, 64);
        unsigned long long lo = umin64(k1, ok1);
        unsigned long long hi = umax64(k1, ok1);
        k2 = umin64(hi, umin64(k2, ok2));
        k1 = lo;
    }

    if (l < 16) {
        int fidx = (int)(unsigned)(k1 & 0xFFFFFFFFull);
        const float d1f = key_to_float((unsigned)(k1 >> 32));
        const float d2f = key_to_float((unsigned)(k2 >> 32));
        if (d2f - d1f < MARGIN) {
            // exact fp32 rescore of the two candidates (bit-exact R1 chain)
            const int ia = fidx;
            const int ib = (int)(unsigned)(k2 & 0xFFFFFFFFull);
            const float4* zr = (const float4*)z + (size_t)tokG * 16;
            const float4* ca = (const float4*)cb + (size_t)ia * 16;
            const float4* cbp = (const float4*)cb + (size_t)ib * 16;
            float sa = 0.f, sb = 0.f;
#pragma unroll
            for (int j = 0; j < 16; ++j) {
                float4 xv = zr[j];
                float4 va = ca[j], vb = cbp[j];
                sa = fmaf(xv.x, va.x, sa); sb = fmaf(xv.x, vb.x, sb);
                sa = fmaf(xv.y, va.y, sa); sb = fmaf(xv.y, vb.y, sb);
                sa = fmaf(xv.z, va.z, sa); sb = fmaf(xv.z, vb.z, sb);
                sa = fmaf(xv.w, va.w, sa); sb = fmaf(xv.w, vb.w, sb);
            }
            const float ea = fmaf(-2.f, sa, cn_lds[ia]);   // exact R1 distance
            const float eb = fmaf(-2.f, sb, cn_lds[ib]);
            const unsigned long long ka = ((unsigned long long)order_key(ea) << 32) | (unsigned)ia;
            const unsigned long long kb = ((unsigned long long)order_key(eb) << 32) | (unsigned)ib;
            fidx = (int)(unsigned)(umin64(ka, kb) & 0xFFFFFFFFull);
        }
        win[tokL] = fidx;
        atomicAdd(&ws[WS_CNT + fidx], 1.f);   // integer-valued: exact, order-indep
    }
    __syncthreads();

    // ---- fused epilogue: z_q_bar + commit-loss partial (z re-read, L2-hot) ----
    {
        const int tokr = t >> 2, fb = (t & 3) * 4;   // 4 threads per token
        const int idx = win[tokr];
        const float4* zr = (const float4*)z + (size_t)(tok0 + tokr) * 16;
        const float4* cq = (const float4*)cb + (size_t)idx * 16;
        float4* o4 = (float4*)out + (size_t)(tok0 + tokr) * 16;
        float ss = 0.f;
#pragma unroll
        for (int j = 0; j < 4; ++j) {
            float4 xv = zr[fb + j];
            float4 qv = cq[fb + j];
            float4 ov; float dx;
            dx = qv.x - xv.x; ov.x = xv.x + dx; ss = fmaf(dx, dx, ss);
            dx = qv.y - xv.y; ov.y = xv.y + dx; ss = fmaf(dx, dx, ss);
            dx = qv.z - xv.z; ov.z = xv.z + dx; ss = fmaf(dx, dx, ss);
            dx = qv.w - xv.w; ov.w = xv.w + dx; ss = fmaf(dx, dx, ss);
            o4[fb + j] = ov;
        }
        ss += __shfl_down(ss, 2, 64);   // quadrants: (q0+q2)
        ss += __shfl_down(ss, 1, 64);   // + (q1+q3)
        if ((t & 3) == 0) lsum[tokr] = ss * (1.f / 64.f);
    }
    __syncthreads();
    if (t < 64) {
        float v = lsum[t];
#pragma unroll
        for (int off = 32; off > 0; off >>= 1) v += __shfl_down(v, off, 64);
        if (t == 0) ws[WS_LOSS + blk] = v;
    }
}

// Reduce-only final (shuffle trees; R12/R13-proven logic). 1 block x 1024 thr.
__global__ void final_kernel(const float* __restrict__ ws, float* __restrict__ out) {
    const int t = threadIdx.x;          // 0..1023
    const int l = t & 63, wv = t >> 6;  // 16 waves
    __shared__ float rbuf[16];

#define BLOCK_REDUCE(VAR, EXPR)                                             \
    float VAR;                                                              \
    {                                                                       \
        float v_ = (EXPR);                                                  \
        _Pragma("unroll")                                                   \
        for (int off = 32; off > 0; off >>= 1) v_ += __shfl_down(v_, off, 64); \
        if (l == 0) rbuf[wv] = v_;                                          \
        __syncthreads();                                                    \
        float r_ = (t < 16) ? rbuf[t] : 0.f;                                \
        if (wv == 0) {                                                      \
            _Pragma("unroll")                                               \
            for (int off = 8; off > 0; off >>= 1) r_ += __shfl_down(r_, off, 64); \
            if (l == 0) rbuf[0] = r_;                                       \
        }                                                                   \
        __syncthreads();                                                    \
        VAR = rbuf[0];                                                      \
        __syncthreads();                                                    \
    }

    const float c = ws[WS_CNT + t];
    BLOCK_REDUCE(totraw, c)
    const float total = fmaxf(totraw, 1e-6f);
    const float p = c / total;
    BLOCK_REDUCE(ent, p * logf(p + 1e-7f))
    BLOCK_REDUCE(used, (c >= 1.f) ? 1.f : 0.f)
    BLOCK_REDUCE(loss, ws[WS_LOSS + t])
#undef BLOCK_REDUCE

    if (t == 0) {
        out[OUT_SCALARS + 0] = loss * (1.f / (float)NTOK);
        out[OUT_SCALARS + 1] = expf(-ent);
        out[OUT_SCALARS + 2] = used * (1.f / (float)KCODE);
    }
}

extern "C" void kernel_launch(void* const* d_in, const int* in_sizes, int n_in,
                              void* d_out, int out_size, void* d_ws, size_t ws_size,
                              hipStream_t stream) {
    const float* z  = (const float*)d_in[0];
    const float* cb = (const float*)d_in[1];
    float* out = (float*)d_out;
    float* ws  = (float*)d_ws;   // ~344 KB used

    prep_kernel <<<4, 256, 0, stream>>>(cb, ws);
    quant_kernel<<<NTOK / 64, 256, 0, stream>>>(z, cb, out, ws);
    final_kernel<<<1, 1024, 0, stream>>>(ws, out);
}